// Round 15
// baseline (231.836 us; speedup 1.0000x reference)
//
#include <hip/hip_runtime.h>

#define D 128
#define DA 16
#define CAP 64
#define SCB 1024   // scatter blocks appended to NT dispatch

typedef unsigned int uint;
typedef __attribute__((ext_vector_type(8))) short bf16x8;
typedef __attribute__((ext_vector_type(4))) float f32x4;
typedef __attribute__((ext_vector_type(2))) float f32x2;

__device__ __forceinline__ uint rne16(float f) {
    uint u = __float_as_uint(f);
    return (u + 0x7FFFu + ((u >> 16) & 1u)) >> 16;
}
__device__ __forceinline__ uint pack2(float lo, float hi) {
    return rne16(lo) | (rne16(hi) << 16);
}
__device__ __forceinline__ float bflo(uint u) { return __uint_as_float(u << 16); }
__device__ __forceinline__ float bfhi(uint u) { return __uint_as_float(u & 0xFFFF0000u); }

// ---------------------------------------------------------------------------
// Dispatch 1: transpose W0,W1,Win,Wout -> bf16 [col][k]  +  zero cnt inline.
// ---------------------------------------------------------------------------
__global__ __launch_bounds__(256) void wtrans_zero_kernel(
    const float* __restrict__ W0, const float* __restrict__ W1,
    const float* __restrict__ Win, const float* __restrict__ Wout,
    ushort* __restrict__ wt, int* __restrict__ cnt, int N)
{
    int gid = blockIdx.x * 256 + threadIdx.x;   // 0..65535
    for (int g = gid; g < N; g += 65536) cnt[g] = 0;
    int m   = gid >> 14;
    int r   = gid & 16383;
    int col = r >> 7;
    int k   = r & 127;
    const float* W = (m == 0) ? W0 : (m == 1) ? W1 : (m == 2) ? Win : Wout;
    wt[(size_t)m * 16384 + (size_t)col * 128 + k] =
        (ushort)rne16(W[(size_t)k * 128 + col]);
}

// ---------------------------------------------------------------------------
// Dispatch 2 (fused): blocks [0,nblk): NT (MFMA h0/h1 transform);
// blocks [nblk, nblk+SCB): bucket-scatter edges by dst (overlaps NT on CUs).
// srt record: {s0 | s1<<16, e}
// ---------------------------------------------------------------------------
__global__ __launch_bounds__(256) void nt_scatter_kernel(
    const float* __restrict__ x,
    const ushort* __restrict__ w0t, const ushort* __restrict__ w1t,
    const float* __restrict__ b0, const float* __restrict__ b1,
    ushort* __restrict__ h0b, ushort* __restrict__ h1b,
    const int* __restrict__ idx, int* __restrict__ cnt, uint2* __restrict__ srt,
    int N, int E, int nblk)
{
    const int t = threadIdx.x;
    if (blockIdx.x >= nblk) {
        // ---- scatter role ----
        const int sb = blockIdx.x - nblk;
        const int stride = SCB * 256;
        for (int e = sb * 256 + t; e < E; e += stride) {
            int dst = idx[e];
            uint s0 = (uint)idx[(long)E + e];
            uint s1 = (uint)idx[2L * E + e];
            int pos = atomicAdd(&cnt[dst], 1);
            if (pos < CAP)
                srt[(size_t)dst * CAP + pos] = make_uint2(s0 | (s1 << 16), (uint)e);
        }
        return;
    }
    // ---- NT role ----
    const int w = t >> 6;
    const int lane = t & 63;
    const int lc = lane & 15;
    const int row0 = blockIdx.x * 64;
    const int arow = row0 + w * 16 + lc;
    const int asrc = (arow < N) ? arow : (N - 1);
    const int k0 = (lane >> 4) * 8;

    f32x4 acc0[8], acc1[8];
    #pragma unroll
    for (int c = 0; c < 8; c++) {
        acc0[c] = (f32x4){0.f, 0.f, 0.f, 0.f};
        acc1[c] = (f32x4){0.f, 0.f, 0.f, 0.f};
    }

    #pragma unroll
    for (int kc = 0; kc < D; kc += 32) {
        const float* ap = x + (size_t)asrc * D + kc + k0;
        float4 v0 = *(const float4*)ap;
        float4 v1 = *(const float4*)(ap + 4);
        bf16x8 af;
        af[0]=(short)rne16(v0.x); af[1]=(short)rne16(v0.y);
        af[2]=(short)rne16(v0.z); af[3]=(short)rne16(v0.w);
        af[4]=(short)rne16(v1.x); af[5]=(short)rne16(v1.y);
        af[6]=(short)rne16(v1.z); af[7]=(short)rne16(v1.w);
        #pragma unroll
        for (int c = 0; c < 8; c++) {
            int col = c * 16 + lc;
            bf16x8 bf0 = *(const bf16x8*)(w0t + (size_t)col * 128 + kc + k0);
            bf16x8 bf1 = *(const bf16x8*)(w1t + (size_t)col * 128 + kc + k0);
            acc0[c] = __builtin_amdgcn_mfma_f32_16x16x32_bf16(af, bf0, acc0[c], 0, 0, 0);
            acc1[c] = __builtin_amdgcn_mfma_f32_16x16x32_bf16(af, bf1, acc1[c], 0, 0, 0);
        }
    }
    const int crow0 = row0 + w * 16 + (lane >> 4) * 4;
    #pragma unroll
    for (int c = 0; c < 8; c++) {
        int col = c * 16 + lc;
        float bb0 = b0[col], bb1 = b1[col];
        #pragma unroll
        for (int r = 0; r < 4; r++) {
            int gr = crow0 + r;
            if (gr < N) {
                h0b[(size_t)gr * D + col] = (ushort)rne16(acc0[c][r] + bb0);
                h1b[(size_t)gr * D + col] = (ushort)rne16(acc1[c][r] + bb1);
            }
        }
    }
}

// ---------------------------------------------------------------------------
// Dispatch 3 (fused pull + MLP): block = 16 nodes, 512 threads (8 waves).
// Pull phase: wave w handles nodes w*2, w*2+1 (r14 inner loop, reg-lean);
// agg rows -> LDS bf16 (no global round-trip). MLP phase: 16 rows x 128 cols,
// wave w does one 16x16 col-tile; T reuses the same LDS buffer.
// 4 blocks/CU (launch_bounds 512,8) so other blocks backfill pull stragglers.
// ---------------------------------------------------------------------------
__global__ __launch_bounds__(512, 8) void pull_mlp_kernel(
    const uint2* __restrict__ srt, const int* __restrict__ cnt,
    const float* __restrict__ a, const float* __restrict__ Wa, const float* __restrict__ ba,
    const ushort* __restrict__ h0b, const ushort* __restrict__ h1b,
    const float* __restrict__ x, const float* __restrict__ epsp,
    const ushort* __restrict__ wint, const float* __restrict__ bin,
    const ushort* __restrict__ woutt, const float* __restrict__ bout,
    float* __restrict__ out, int N)
{
    __shared__ __align__(16) short buf[16][136];   // agg (phase A/B1), then T (B2)
    const int t = threadIdx.x;
    const int w = t >> 6;          // 0..7
    const int lane = t & 63;
    const int c2 = lane * 2;
    const int row0 = blockIdx.x * 16;

    // ---- Phase A: pull 2 nodes per wave ----
    {
        f32x2 waT[DA];
        #pragma unroll
        for (int j = 0; j < DA; j++) waT[j] = *(const f32x2*)(Wa + j * D + c2);
        const f32x2 bav = *(const f32x2*)(ba + c2);

        #pragma unroll
        for (int i = 0; i < 2; i++) {
            const int local = w * 2 + i;
            const int wid = row0 + local;
            f32x2 acc = (f32x2){0.f, 0.f};
            if (wid < N) {
                int deg = __builtin_amdgcn_readfirstlane(cnt[wid]);
                if (deg > CAP) deg = CAP;
                const uint2 recs = (lane < deg) ? srt[(size_t)wid * CAP + lane]
                                                : make_uint2(0u, 0u);
                #pragma unroll 4
                for (int ei = 0; ei < deg; ei++) {
                    const uint s01 = (uint)__builtin_amdgcn_readlane((int)recs.x, ei);
                    const uint e_u = (uint)__builtin_amdgcn_readlane((int)recs.y, ei);
                    const uint s0 = s01 & 0xFFFFu;
                    const uint s1 = s01 >> 16;
                    const float4* ap = (const float4*)(a + (size_t)e_u * DA);
                    float av[DA];
                    *(float4*)&av[0]  = ap[0];
                    *(float4*)&av[4]  = ap[1];
                    *(float4*)&av[8]  = ap[2];
                    *(float4*)&av[12] = ap[3];
                    uint u0 = *(const uint*)(h0b + (size_t)s0 * D + c2);
                    uint u1 = *(const uint*)(h1b + (size_t)s1 * D + c2);
                    f32x2 m;
                    m.x = bflo(u0) + bflo(u1) + bav.x;
                    m.y = bfhi(u0) + bfhi(u1) + bav.y;
                    #pragma unroll
                    for (int j = 0; j < DA; j++) {
                        f32x2 avv = (f32x2){av[j], av[j]};
                        m = m + avv * waT[j];
                    }
                    f32x2 r;
                    r.x = fmaxf(m.x, 0.0f);
                    r.y = fmaxf(m.y, 0.0f);
                    acc = acc + r;
                }
            }
            *(uint*)&buf[local][c2] = pack2(acc.x, acc.y);
        }
    }
    __syncthreads();

    // ---- Phase B: MLP on 16 rows. wave w -> cols w*16..w*16+15 ----
    const int lc = lane & 15;
    const int k0 = (lane >> 4) * 8;
    const int cbase = w * 16;
    const int col = cbase + lc;
    const int arow = row0 + lc;
    const int asrc = (arow < N) ? arow : (N - 1);
    const float epsv = 1.0f + epsp[0];

    f32x4 acc = (f32x4){0.f, 0.f, 0.f, 0.f};

    // B1: acc = (x*(1+eps)+agg) @ Win   (agg from LDS)
    #pragma unroll
    for (int kc = 0; kc < D; kc += 32) {
        const float* xp = x + (size_t)asrc * D + kc + k0;
        float4 x0 = *(const float4*)xp;
        float4 x1 = *(const float4*)(xp + 4);
        bf16x8 ag = *(const bf16x8*)&buf[lc][kc + k0];
        bf16x8 af;
        af[0]=(short)rne16(x0.x*epsv + __uint_as_float(((uint)(ushort)ag[0]) << 16));
        af[1]=(short)rne16(x0.y*epsv + __uint_as_float(((uint)(ushort)ag[1]) << 16));
        af[2]=(short)rne16(x0.z*epsv + __uint_as_float(((uint)(ushort)ag[2]) << 16));
        af[3]=(short)rne16(x0.w*epsv + __uint_as_float(((uint)(ushort)ag[3]) << 16));
        af[4]=(short)rne16(x1.x*epsv + __uint_as_float(((uint)(ushort)ag[4]) << 16));
        af[5]=(short)rne16(x1.y*epsv + __uint_as_float(((uint)(ushort)ag[5]) << 16));
        af[6]=(short)rne16(x1.z*epsv + __uint_as_float(((uint)(ushort)ag[6]) << 16));
        af[7]=(short)rne16(x1.w*epsv + __uint_as_float(((uint)(ushort)ag[7]) << 16));
        bf16x8 bf = *(const bf16x8*)(wint + (size_t)col * 128 + kc + k0);
        acc = __builtin_amdgcn_mfma_f32_16x16x32_bf16(af, bf, acc, 0, 0, 0);
    }
    __syncthreads();   // all agg reads done; buf reused for T

    // T = relu(acc + bin) -> buf (bf16)
    {
        const int trow0 = (lane >> 4) * 4;
        float bb = bin[col];
        #pragma unroll
        for (int r = 0; r < 4; r++)
            buf[trow0 + r][col] = (short)rne16(fmaxf(acc[r] + bb, 0.0f));
        acc = (f32x4){0.f, 0.f, 0.f, 0.f};
    }
    __syncthreads();

    // B2: out = T @ Wout + bout
    #pragma unroll
    for (int kc = 0; kc < D; kc += 32) {
        bf16x8 af = *(const bf16x8*)&buf[lc][kc + k0];
        bf16x8 bf = *(const bf16x8*)(woutt + (size_t)col * 128 + kc + k0);
        acc = __builtin_amdgcn_mfma_f32_16x16x32_bf16(af, bf, acc, 0, 0, 0);
    }
    const int crow0 = row0 + (lane >> 4) * 4;
    float bb = bout[col];
    #pragma unroll
    for (int r = 0; r < 4; r++) {
        int gr = crow0 + r;
        if (gr < N) out[(size_t)gr * D + col] = acc[r] + bb;
    }
}

extern "C" void kernel_launch(void* const* d_in, const int* in_sizes, int n_in,
                              void* d_out, int out_size, void* d_ws, size_t ws_size,
                              hipStream_t stream)
{
    const float* x    = (const float*)d_in[0];
    const int*   idx  = (const int*)  d_in[1];
    const float* a    = (const float*)d_in[2];
    const float* W0   = (const float*)d_in[3];
    const float* b0   = (const float*)d_in[4];
    const float* W1   = (const float*)d_in[5];
    const float* b1   = (const float*)d_in[6];
    const float* Wa   = (const float*)d_in[7];
    const float* ba   = (const float*)d_in[8];
    const float* eps  = (const float*)d_in[9];
    const float* Win  = (const float*)d_in[10];
    const float* bin  = (const float*)d_in[11];
    const float* Wout = (const float*)d_in[12];
    const float* bout = (const float*)d_in[13];
    float* out = (float*)d_out;

    const int N = in_sizes[0] / D;
    const int E = in_sizes[1] / 3;

    // ws layout: srt(uint2, N*CAP) | h0b | h1b | cnt | wt
    uint2*  srt  = (uint2*)d_ws;
    ushort* h0b  = (ushort*)(srt + (size_t)N * CAP);
    ushort* h1b  = h0b + (size_t)N * D;
    int*    cnt  = (int*)(h1b + (size_t)N * D);
    ushort* wt   = (ushort*)(cnt + ((N + 3) & ~3));
    ushort* w0t   = wt;
    ushort* w1t   = wt + 16384;
    ushort* wint  = wt + 2 * 16384;
    ushort* woutt = wt + 3 * 16384;

    wtrans_zero_kernel<<<256, 256, 0, stream>>>(W0, W1, Win, Wout, wt, cnt, N);

    const int nblk = (N + 63) / 64;
    nt_scatter_kernel<<<nblk + SCB, 256, 0, stream>>>(
        x, w0t, w1t, b0, b1, h0b, h1b, idx, cnt, srt, N, E, nblk);

    const int fblk = (N + 15) / 16;   // 16 nodes per 512-thread block
    pull_mlp_kernel<<<fblk, 512, 0, stream>>>(srt, cnt, a, Wa, ba, h0b, h1b,
                                              x, eps, wint, bin, woutt, bout, out, N);
}